// Round 13
// baseline (2223.964 us; speedup 1.0000x reference)
//
#include <hip/hip_runtime.h>
#include <math.h>

#define EDGES 360000
#define NODES 30000
#define NB_SCAN 118   // ceil(30000/256)
#define EPB 48        // edges per block (360000 = 48*7500 exact)

typedef _Float16 h2 __attribute__((ext_vector_type(2)));
typedef _Float16 h8 __attribute__((ext_vector_type(8)));

__device__ inline int imin(int a, int b){ return a < b ? a : b; }
__device__ inline int imax(int a, int b){ return a > b ? a : b; }

__device__ __forceinline__ float fdot2h(h2 a, h2 b, float c){
#if __has_builtin(__builtin_amdgcn_fdot2)
  return __builtin_amdgcn_fdot2(a, b, c, false);
#else
  return c + (float)a[0]*(float)b[0] + (float)a[1]*(float)b[1];
#endif
}

__device__ __forceinline__ float softplusf(float v){
  return fmaxf(v, 0.f) + log1pf(expf(-fabsf(v)));
}

// ======================= Wigner-3j (CG) on-device init ======================

struct cplx { double re, im; };
__device__ inline cplx cmul(cplx a, cplx b){ return { a.re*b.re - a.im*b.im, a.re*b.im + a.im*b.re }; }

__device__ __constant__ double FACT[9] = {1.0,1.0,2.0,6.0,24.0,120.0,720.0,5040.0,40320.0};

__device__ double su2_cg(int j1,int m1,int j2,int m2,int j3,int m3){
  if (m3 != m1 + m2) return 0.0;
  int vmin = imax(imax(-j1 + j2 + m3, -j1 + m1), 0);
  int vmax = imin(imin(j2 + j3 + m1, j3 - j1 + j2), j3 + m3);
  if (vmax < vmin) return 0.0;
  double c = sqrt((2.0*j3 + 1.0) * FACT[j3+j1-j2] * FACT[j3-j1+j2] * FACT[j1+j2-j3]
                  * FACT[j3+m3] * FACT[j3-m3]
                  / (FACT[j1+j2+j3+1] * FACT[j1-m1] * FACT[j1+m1] * FACT[j2-m2] * FACT[j2+m2]));
  double s = 0.0;
  for (int v = vmin; v <= vmax; ++v){
    double t = FACT[j2+j3+m1-v] * FACT[j1-m1+v]
             / (FACT[v] * FACT[j3-j1+j2-v] * FACT[j3+m3-v] * FACT[v+j1-j2-m3]);
    s += (((v + j2 + m2) & 1) ? -t : t);
  }
  return c * s;
}

__device__ cplx qval(int l, int r, int c){
  const double s = 0.7071067811865476;
  int m = r - l;
  cplx v = {0.0, 0.0};
  if (m < 0){
    if      (c == l - m) v = { s, 0.0 };
    else if (c == l + m) v = { 0.0, -s };
  } else if (m == 0){
    if (c == l) v = { 1.0, 0.0 };
  } else {
    double sg = (m & 1) ? -1.0 : 1.0;
    if      (c == l + m) v = { sg*s, 0.0 };
    else if (c == l - m) v = { 0.0, sg*s };
  }
  switch (l & 3){
    case 0: return v;
    case 1: return {  v.im, -v.re };
    case 2: return { -v.re, -v.im };
    default:return { -v.im,  v.re };
  }
}

struct Combo { int l1, l2, l3, off; };
__device__ __constant__ Combo COMBOS[18] = {
  {0,0,0,0},{0,1,1,1},{0,2,2,10},{1,0,1,35},{1,1,0,44},{1,1,1,53},{1,1,2,80},
  {1,2,1,125},{1,2,2,170},{1,2,3,245},{2,0,2,350},{2,1,1,375},{2,1,2,420},
  {2,1,3,495},{2,2,0,600},{2,2,1,625},{2,2,2,700},{2,2,3,825}
};

__global__ void init_cg_kernel(float* __restrict__ cg){
  __shared__ double sr[175], si[175];
  __shared__ double snorm[2];
  const Combo cb = COMBOS[blockIdx.x];
  const int d1 = 2*cb.l1+1, d2 = 2*cb.l2+1, d3 = 2*cb.l3+1;
  const int tot = d1*d2*d3;
  for (int idx = threadIdx.x; idx < tot; idx += blockDim.x){
    int j = idx/(d2*d3), rem = idx - j*(d2*d3);
    int l = rem/d3, m = rem - l*d3;
    double ar = 0.0, ai = 0.0;
    for (int i = 0; i < d1; ++i){
      cplx q1 = qval(cb.l1, i, j);
      if (q1.re == 0.0 && q1.im == 0.0) continue;
      for (int k = 0; k < d2; ++k){
        cplx q2 = qval(cb.l2, k, l);
        if (q2.re == 0.0 && q2.im == 0.0) continue;
        cplx q12 = cmul(q1, q2);
        for (int n = 0; n < d3; ++n){
          double g = su2_cg(cb.l1, i-cb.l1, cb.l2, k-cb.l2, cb.l3, n-cb.l3);
          if (g == 0.0) continue;
          cplx q3 = qval(cb.l3, n, m); q3.im = -q3.im;
          cplx t = cmul(q12, q3);
          ar += t.re * g; ai += t.im * g;
        }
      }
    }
    sr[idx] = ar; si[idx] = ai;
  }
  __syncthreads();
  if (threadIdx.x == 0){
    double nr = 0.0, ni = 0.0;
    for (int t = 0; t < tot; ++t){ nr += sr[t]*sr[t]; ni += si[t]*si[t]; }
    snorm[0] = nr; snorm[1] = ni;
  }
  __syncthreads();
  const bool useR = snorm[0] >= snorm[1];
  const double inv = 1.0 / sqrt(useR ? snorm[0] : snorm[1]);
  for (int idx = threadIdx.x; idx < tot; idx += blockDim.x)
    cg[cb.off + idx] = (float)((useR ? sr[idx] : si[idx]) * inv);
}

// ======================= layer definitions =================================

struct InsT { int l1,l2,l3,m1,m3,s1,s2,so,woff,cg; float alpha; };

struct L1 {
  static constexpr int NIN = 16, NOUT = 32, WN = 320, NI = 3, NWIN = 5, NU = 16, SW = 322;
  static constexpr InsT ins[NI] = {
    {0,0,0,16,16, 0,0, 0,   0,  0, 0.25f},
    {0,1,1,16, 2, 0,1,16, 256,  1, 0.4330127019f},
    {0,2,2,16, 2, 0,4,22, 288, 10, 0.5590169944f},
  };
  static constexpr int uT [NU] = {0,0,0,0,0,0,0,0, 1,1,1,1, 2,2,2,2};
  static constexpr int uCh[NU] = {0,1,2,3,4,5,6,7, 0,1,2,3, 0,1,2,3};
  static constexpr int uD0[NU] = {0,0,0,0,0,0,0,0, 0,0,0,0, 0,0,0,0};
  static constexpr int uND[NU] = {2,2,2,2,2,2,2,2, 4,4,4,4, 4,4,4,4};
  static constexpr int uPt[NU] = {0,0,0,0,0,0,0,0, 1,1,1,1, 1,1,1,1};
};
struct L2 {
  static constexpr int NIN = 32, NOUT = 48, WN = 424, NI = 15, NWIN = 7, NU = 30, SW = 426;
  static constexpr InsT ins[NI] = {
    {0,0,0,16,16, 0,0, 0,   0,  0, 0.2236067977f},
    {0,1,1,16, 2, 0,1,16, 256,  1, 0.3692744729f},
    {0,2,2,16, 2, 0,4,28, 288, 10, 0.4767312946f},
    {1,0,1, 2, 2,16,0,16, 320, 35, 0.3692744729f},
    {1,1,0, 2,16,16,1, 0, 324, 44, 0.2236067977f},
    {1,1,1, 2, 2,16,1,22, 356, 53, 0.8660254038f},
    {1,1,2, 2, 2,16,1,28, 360, 80, 0.4767312946f},
    {1,2,1, 2, 2,16,4,16, 364,125, 0.3692744729f},
    {1,2,2, 2, 2,16,4,38, 368,170, 1.1180339887f},
    {2,0,2, 2, 2,22,0,28, 372,350, 0.4767312946f},
    {2,1,1, 2, 2,22,1,16, 376,375, 0.3692744729f},
    {2,1,2, 2, 2,22,1,38, 380,420, 1.1180339887f},
    {2,2,0, 2,16,22,4, 0, 384,600, 0.2236067977f},
    {2,2,1, 2, 2,22,4,22, 416,625, 0.8660254038f},
    {2,2,2, 2, 2,22,4,28, 420,700, 0.4767312946f},
  };
  static constexpr int uT [NU] = {0,0,0,0,0,0,0,0, 1,1,1,1, 2,2,2,2, 3, 4,4, 5, 6,7,8, 9,10,11, 12,12, 13,14};
  static constexpr int uCh[NU] = {0,1,2,3,4,5,6,7, 0,1,2,3, 0,1,2,3, 0, 0,0, 0, 0,0,0, 0,0,0, 0,0, 0,0};
  static constexpr int uD0[NU] = {0,0,0,0,0,0,0,0, 0,0,0,0, 0,0,0,0, 0, 0,1, 0, 0,0,0, 0,0,0, 0,1, 0,0};
  static constexpr int uND[NU] = {2,2,2,2,2,2,2,2, 4,4,4,4, 4,4,4,4, 2, 1,1, 2, 2,2,2, 2,2,2, 1,1, 2,2};
  static constexpr int uPt[NU] = {0,0,0,0,0,0,0,0, 1,1,1,1, 1,1,1,1, 1, 0,0, 1, 1,1,1, 1,1,1, 0,0, 1,1};
};
struct L3 {
  static constexpr int NIN = 48, NOUT = 64, WN = 216, NI = 33, NWIN = 4, NU = 42, SW = 218;
  static constexpr InsT ins[NI] = {
    {0,0,0,16,2, 0,0, 0,   0,  0, 0.2236067977f},
    {0,1,1,16,2, 0,1,10,  32,  1, 0.3396831102f},
    {0,2,2,16,2, 0,4,16,  64, 10, 0.4385290097f},
    {1,0,1, 2,2,16,0,10,  96, 35, 0.3396831102f},
    {1,1,0, 2,2,16,1, 0, 100, 44, 0.2236067977f},
    {1,1,1, 2,2,16,1, 4, 104, 53, 0.5477225575f},
    {1,1,2, 2,2,16,1,16, 108, 80, 0.4385290097f},
    {1,2,1, 2,2,16,4,10, 112,125, 0.3396831102f},
    {1,2,2, 2,2,16,4,26, 116,170, 0.7071067812f},
    {1,2,3, 2,2,16,4,50, 120,245, 1.0801234497f},
    {1,0,1, 2,2,22,0, 4, 124, 35, 0.5477225575f},
    {1,1,0, 2,2,22,1, 2, 128, 44, 0.5f},
    {1,1,1, 2,2,22,1,10, 132, 53, 0.3396831102f},
    {1,1,2, 2,2,22,1,26, 136, 80, 0.7071067812f},
    {1,2,1, 2,2,22,4, 4, 140,125, 0.5477225575f},
    {1,2,2, 2,2,22,4,16, 144,170, 0.4385290097f},
    {1,2,3, 2,2,22,4,36, 148,245, 1.0801234497f},
    {2,0,2, 2,2,28,0,16, 152,350, 0.4385290097f},
    {2,1,1, 2,2,28,1,10, 156,375, 0.3396831102f},
    {2,1,2, 2,2,28,1,26, 160,420, 0.7071067812f},
    {2,1,3, 2,2,28,1,50, 164,495, 1.0801234497f},
    {2,2,0, 2,2,28,4, 0, 168,600, 0.2236067977f},
    {2,2,1, 2,2,28,4, 4, 172,625, 0.5477225575f},
    {2,2,2, 2,2,28,4,16, 176,700, 0.4385290097f},
    {2,2,3, 2,2,28,4,36, 180,825, 1.0801234497f},
    {2,0,2, 2,2,38,0,26, 184,350, 0.7071067812f},
    {2,1,1, 2,2,38,1, 4, 188,375, 0.5477225575f},
    {2,1,2, 2,2,38,1,16, 192,420, 0.4385290097f},
    {2,1,3, 2,2,38,1,36, 196,495, 1.0801234497f},
    {2,2,0, 2,2,38,4, 2, 200,600, 0.5f},
    {2,2,1, 2,2,38,4,10, 204,625, 0.3396831102f},
    {2,2,2, 2,2,38,4,26, 208,700, 0.7071067812f},
    {2,2,3, 2,2,38,4,50, 212,825, 1.0801234497f},
  };
  static constexpr int uT [NU] = {0,0,0,0, 1,1,1,1, 2,2,2,2,
    3,4,5,6,7,8,9,10,11,12,13,14,15,16,17,18,19,20,21,22,23,24,25,26,27,28,29,30,31,32};
  static constexpr int uCh[NU] = {0,1,2,3, 0,1,2,3, 0,1,2,3,
    0,0,0,0,0,0,0,0,0,0,0,0,0,0,0,0,0,0,0,0,0,0,0,0,0,0,0,0,0,0};
  static constexpr int uD0[NU] = {0,0,0,0, 0,0,0,0, 0,0,0,0,
    0,0,0,0,0,0,0,0,0,0,0,0,0,0,0,0,0,0,0,0,0,0,0,0,0,0,0,0,0,0};
  static constexpr int uND[NU] = {4,4,4,4, 4,4,4,4, 4,4,4,4,
    2,2,2,2,2,2,2,2,2,2,2,2,2,2,2,2,2,2,2,2,2,2,2,2,2,2,2,2,2,2};
  static constexpr int uPt[NU] = {0,0,0,0, 0,0,0,0, 0,0,0,0,
    0,0,0,0,0,0,1,0,0,0,0,0,0,1,0,0,0,1,0,0,0,1,0,0,0,1,0,0,0,1};
};

// ======================= constexpr helpers =================================

template<class LD>
constexpr int colsum(){
  int s = 0;
  for (int u = 0; u < LD::NU; ++u) s += LD::uND[u] * LD::ins[LD::uT[u]].m3;
  return s;
}
static_assert(colsum<L1>() == L1::WN, "L1 col coverage");
static_assert(colsum<L2>() == L2::WN, "L2 col coverage");
static_assert(colsum<L3>() == L3::WN, "L3 col coverage");

template<class LD, int PART>
constexpr int soLo(){
  int lo = 1 << 20;
  for (int u = 0; u < LD::NU; ++u){
    if (LD::uPt[u] != PART) continue;
    const InsT I = LD::ins[LD::uT[u]];
    if (I.so < lo) lo = I.so;
  }
  return lo;
}
template<class LD, int PART>
constexpr int soHi(){
  int hi = 0;
  for (int u = 0; u < LD::NU; ++u){
    if (LD::uPt[u] != PART) continue;
    const InsT I = LD::ins[LD::uT[u]];
    const int e = I.so + I.m3 * (2*I.l3 + 1);
    if (e > hi) hi = e;
  }
  return hi;
}
static_assert(soHi<L1,0>() == soLo<L1,1>() && soHi<L1,1>() == L1::NOUT && soLo<L1,0>() == 0, "L1 parts");
static_assert(soHi<L2,0>() == soLo<L2,1>() && soHi<L2,1>() == L2::NOUT && soLo<L2,0>() == 0, "L2 parts");
static_assert(soHi<L3,0>() == soLo<L3,1>() && soHi<L3,1>() == L3::NOUT && soLo<L3,0>() == 0, "L3 parts");

// ======================= TP units (straight-line, barrier-free) ============
// a from LDS row; outv accumulates in a PRIVATE LDS row (ov) — no big
// register arrays anywhere in phase 3, so nothing can spill to scratch.

template<class LD, int PART, int U>
__device__ __forceinline__ void tp_units(const char* wrow,
    const float* arow, const float* __restrict__ cgp,
    const float (&sh)[9], float* ov)
{
  if constexpr (U < LD::NU) {
    if constexpr (LD::uPt[U] == PART) {
      constexpr InsT I = LD::ins[LD::uT[U]];
      constexpr int d1 = 2*I.l1+1, d2 = 2*I.l2+1, d3 = 2*I.l3+1;
      constexpr int UCH = (I.m3 == 16) ? 2 : (I.m1 == 16 ? 4 : 2);
      constexpr int base = I.woff + LD::uCh[U] * UCH * I.m3;
      constexpr int SOLO = soLo<LD,PART>();
      constexpr int D0 = LD::uD0[U];
      constexpr int ND = LD::uND[U];
      #pragma unroll
      for (int dd = 0; dd < ND; ++dd) {
        const int du = D0 + dd;
        const int u  = LD::uCh[U]*UCH + du;
        float ab[d3];
        #pragma unroll
        for (int k = 0; k < d3; ++k) ab[k] = 0.f;
        #pragma unroll
        for (int i = 0; i < d1; ++i) {
          const float ai = arow[I.s1 + u*d1 + i];
          #pragma unroll
          for (int j = 0; j < d2; ++j) {
            const float s = ai * sh[I.s2 + j];
            #pragma unroll
            for (int k = 0; k < d3; ++k)
              ab[k] = fmaf(cgp[I.cg + (i*d2 + j)*d3 + k], s, ab[k]);
          }
        }
        #pragma unroll
        for (int wo2 = 0; wo2 < I.m3/2; ++wo2) {
          const h2 wp = *(const h2*)(wrow + (base + du*I.m3 + 2*wo2)*2);
          const float wv0 = I.alpha * (float)wp[0];
          const float wv1 = I.alpha * (float)wp[1];
          #pragma unroll
          for (int k = 0; k < d3; ++k) {
            const int o0 = I.so - SOLO + (2*wo2  )*d3 + k;
            const int o1 = I.so - SOLO + (2*wo2+1)*d3 + k;
            ov[o0] = fmaf(wv0, ab[k], ov[o0]);
            ov[o1] = fmaf(wv1, ab[k], ov[o1]);
          }
        }
      }
    }
    tp_units<LD, PART, U+1>(wrow, arow, cgp, sh, ov);
  }
}

// ======================= pack w2 to fp16 pair rows =========================
__global__ void pack_w2_kernel(const float* __restrict__ w2, float* __restrict__ dst,
                               int WN){
  const int hp = blockIdx.x;
  for (int c = threadIdx.x; c < WN; c += 256){
    h2 p;
    p[0] = (_Float16)w2[(size_t)(2*hp  )*WN + c];
    p[1] = (_Float16)w2[(size_t)(2*hp+1)*WN + c];
    *(h2*)((char*)dst + ((size_t)hp*WN + c)*4) = p;
  }
}

// ======================= fused conv kernel =================================
// LDS: Wls [48 e][SW fp16] (∪ efsB) | hidB [32 hp][192B] | asB [48][NIN+1 f]
//      | ovB: part0 rows [48][ST0 f], part1 rows [48][ST1 f]

template<class LD>
__launch_bounds__(256, 2)
__global__ void conv_kernel(const float* __restrict__ node_h,
    const float* __restrict__ edge_vec, const float* __restrict__ edge_feat,
    const int* __restrict__ eidx,
    const float* __restrict__ w1, const float* __restrict__ b1,
    const float* __restrict__ w2h, const float* __restrict__ b2,
    const float* __restrict__ cgp, float* __restrict__ tp_out)
{
  constexpr int NIN = LD::NIN, NOUT = LD::NOUT, WN = LD::WN;
  constexpr int NV0 = soHi<LD,0>() - soLo<LD,0>();
  constexpr int NV1 = soHi<LD,1>() - soLo<LD,1>();
  constexpr int ST0 = NV0 | 1;     // odd strides -> conflict-free private rows
  constexpr int ST1 = NV1 | 1;
  constexpr int SB = LD::SW * 2;
  constexpr int WBYTES = EPB * SB;
  constexpr int OFF_HID = WBYTES;
  constexpr int OFF_AS  = WBYTES + 32*192;
  constexpr int OFF_OV  = OFF_AS + EPB*(NIN+1)*4;
  constexpr int SM_BYTES = OFF_OV + EPB*(ST0 + ST1)*4;
  static_assert(SM_BYTES <= 65536, "static LDS limit");
  static_assert(32*192 <= WBYTES, "efsB must fit in W region");
  __shared__ __align__(16) char sm[SM_BYTES];
  char* Wls  = sm;
  char* efsB = sm;                  // alias: dead after FC1
  char* hidB = sm + OFF_HID;        // [32 hp][192B]
  float* asB = (float*)(sm + OFF_AS);
  float* ovB = (float*)(sm + OFF_OV);

  const int t = threadIdx.x;
  const int e0g = blockIdx.x * EPB;

  // ---------- phase 0: stage ef (transposed fp16 pairs) + a (padded) ------
  {
    const float4* efg = (const float4*)edge_feat + (size_t)e0g * 16;
    #pragma unroll
    for (int r = 0; r < 3; ++r) {
      const int f = r*256 + t;                 // f < 768 = 48e*16
      const int e = f >> 4, c0 = (f & 15) * 4;
      const float4 v = efg[f];
      h2 pa; pa[0] = (_Float16)v.x; pa[1] = (_Float16)v.y;
      h2 pb; pb[0] = (_Float16)v.z; pb[1] = (_Float16)v.w;
      *(h2*)(efsB + (c0>>1)*192 + e*4)     = pa;
      *(h2*)(efsB + ((c0>>1)+1)*192 + e*4) = pb;
    }
    for (int i = t; i < EPB*NIN; i += 256) {
      const int e = i / NIN, c = i - e*NIN;
      const int dst = eidx[EDGES + e0g + e];
      asB[e*(NIN+1) + c] = node_h[(size_t)dst*NIN + c];
    }
  }
  __syncthreads();

  // ---------- phase 1: FC1 (hidden = softplus(ef@w1+b1)) -> hidB ----------
  {
    const int hg = t >> 3, eg2 = t & 7;       // hp 0..31, 6 edges each
    const int h0 = hg*2, e0 = eg2*6;
    float acc[2][6];
    const float b10 = b1[h0], b11 = b1[h0+1];
    #pragma unroll
    for (int i = 0; i < 6; ++i) { acc[0][i] = b10; acc[1][i] = b11; }
    for (int cp = 0; cp < 32; ++cp) {
      h2 wp0, wp1;
      wp0[0] = (_Float16)w1[(size_t)(2*cp)*64 + h0];
      wp0[1] = (_Float16)w1[(size_t)(2*cp+1)*64 + h0];
      wp1[0] = (_Float16)w1[(size_t)(2*cp)*64 + h0+1];
      wp1[1] = (_Float16)w1[(size_t)(2*cp+1)*64 + h0+1];
      #pragma unroll
      for (int i = 0; i < 6; ++i) {
        const h2 e2 = *(const h2*)(efsB + cp*192 + (e0+i)*4);
        acc[0][i] = fdot2h(wp0, e2, acc[0][i]);
        acc[1][i] = fdot2h(wp1, e2, acc[1][i]);
      }
    }
    __syncthreads();   // all efsB reads done -> W region writable
    #pragma unroll
    for (int i = 0; i < 6; ++i) {
      h2 p;
      p[0] = (_Float16)softplusf(acc[0][i]);
      p[1] = (_Float16)softplusf(acc[1][i]);
      *(h2*)(hidB + hg*192 + (e0+i)*4) = p;
    }
  }
  __syncthreads();     // hidB complete

  // ---------- phase 2: FC2 over ALL columns -> W LDS (no barriers) --------
  {
    const int eg = t >> 4, cg = t & 15;       // 16 edge-groups x 3e, 16 col-groups x 4c
    const int e0 = eg*3;
    #pragma unroll
    for (int k = 0; k < LD::NWIN; ++k) {
      const int cb = k*64 + cg*4;
      if (cb < WN) {
        float acc[3][4];
        const float4 bv = *(const float4*)&b2[cb];
        const float bb[4] = {bv.x, bv.y, bv.z, bv.w};
        #pragma unroll
        for (int ei = 0; ei < 3; ++ei)
          #pragma unroll
          for (int ci = 0; ci < 4; ++ci) acc[ei][ci] = bb[ci];
        for (int hp = 0; hp < 32; ++hp) {
          const h8 wv = *(const h8*)((const char*)w2h + ((size_t)hp*WN + cb)*4);
          const h2 h0v = *(const h2*)(hidB + hp*192 + (e0+0)*4);
          const h2 h1v = *(const h2*)(hidB + hp*192 + (e0+1)*4);
          const h2 h2v = *(const h2*)(hidB + hp*192 + (e0+2)*4);
          #pragma unroll
          for (int ci = 0; ci < 4; ++ci) {
            const h2 wp = ((const h2*)&wv)[ci];
            acc[0][ci] = fdot2h(h0v, wp, acc[0][ci]);
            acc[1][ci] = fdot2h(h1v, wp, acc[1][ci]);
            acc[2][ci] = fdot2h(h2v, wp, acc[2][ci]);
          }
        }
        #pragma unroll
        for (int ei = 0; ei < 3; ++ei) {
          char* wp = Wls + (e0+ei)*SB + cb*2;
          h2 p0; p0[0] = (_Float16)acc[ei][0]; p0[1] = (_Float16)acc[ei][1];
          h2 p1; p1[0] = (_Float16)acc[ei][2]; p1[1] = (_Float16)acc[ei][3];
          *(h2*)(wp)     = p0;
          *(h2*)(wp + 4) = p1;
        }
      }
    }
  }
  __syncthreads();     // W complete — LAST barrier

  // ---------- phase 3: TP, two edge-parallel parts, barrier-free ----------
  const bool p0 = (t < EPB);
  const bool p1 = (t >= 128 && t < 128 + EPB);
  if (p0 || p1) {
    const int le = p0 ? t : (t - 128);
    const int eme = e0g + le;
    float sh[9];
    {
      const float vx = edge_vec[(size_t)eme*3 + 0];
      const float vy = edge_vec[(size_t)eme*3 + 1];
      const float vz = edge_vec[(size_t)eme*3 + 2];
      const float nrm = sqrtf(vx*vx + vy*vy + vz*vz);
      const float invn = 1.0f / fmaxf(nrm, 1e-12f);
      const float x = vx*invn, y = vy*invn, z = vz*invn;
      sh[0] = 1.0f;
      sh[1] = 1.7320508076f * y;
      sh[2] = 1.7320508076f * z;
      sh[3] = 1.7320508076f * x;
      sh[4] = 3.8729833462f * x * y;
      sh[5] = 3.8729833462f * y * z;
      sh[6] = 1.1180339887f * (3.0f*z*z - 1.0f);
      sh[7] = 3.8729833462f * x * z;
      sh[8] = 1.9364916731f * (x*x - y*y);
    }
    const char* wrow  = Wls + le * SB;
    const float* arow = asB + le * (NIN + 1);
    float* dstp = tp_out + (size_t)eme * NOUT;
    if (p0) {
      float* ov = ovB + le * ST0;
      #pragma unroll
      for (int o = 0; o < NV0; ++o) ov[o] = 0.f;
      tp_units<LD, 0, 0>(wrow, arow, cgp, sh, ov);
      #pragma unroll
      for (int o = 0; o < NV0; ++o) dstp[o] = ov[o];
    } else {
      constexpr int SOLO = soLo<LD,1>();
      float* ov = ovB + EPB*ST0 + le * ST1;
      #pragma unroll
      for (int o = 0; o < NV1; ++o) ov[o] = 0.f;
      tp_units<LD, 1, 0>(wrow, arow, cgp, sh, ov);
      #pragma unroll
      for (int o = 0; o < NV1; ++o) dstp[SOLO + o] = ov[o];
    }
  }
}

// ======================= CSR build kernels =================================

__global__ void cnt_kernel(const int* __restrict__ eidx, int* __restrict__ cnti){
  const int e = blockIdx.x * 256 + threadIdx.x;
  if (e < EDGES) atomicAdd(&cnti[eidx[e]], 1);
}

__global__ void scanA_kernel(const int* __restrict__ cnti, int* __restrict__ escan,
                             int* __restrict__ bsum){
  __shared__ int s[256];
  const int t = threadIdx.x, idx = blockIdx.x*256 + t;
  int v = (idx < NODES) ? cnti[idx] : 0;
  s[t] = v; __syncthreads();
  for (int off = 1; off < 256; off <<= 1){
    int x = (t >= off) ? s[t-off] : 0;
    __syncthreads();
    s[t] += x;
    __syncthreads();
  }
  if (idx < NODES) escan[idx] = s[t];
  if (t == 255) bsum[blockIdx.x] = s[255];
}

__global__ void scanB_kernel(const int* __restrict__ bsum, int* __restrict__ boff){
  __shared__ int s[128];
  const int t = threadIdx.x;
  int v = (t < NB_SCAN) ? bsum[t] : 0;
  s[t] = v; __syncthreads();
  for (int off = 1; off < 128; off <<= 1){
    int x = (t >= off) ? s[t-off] : 0;
    __syncthreads();
    s[t] += x;
    __syncthreads();
  }
  if (t < NB_SCAN) boff[t] = s[t] - v;   // exclusive
}

__global__ void scanC_kernel(const int* __restrict__ escan, const int* __restrict__ cnti,
                             const int* __restrict__ boff, int* __restrict__ eoff,
                             int* __restrict__ ecur){
  const int idx = blockIdx.x*256 + threadIdx.x;
  if (idx < NODES){
    const int v = escan[idx] - cnti[idx] + boff[blockIdx.x];
    eoff[idx] = v; ecur[idx] = v;
  }
  if (idx == 0) eoff[NODES] = EDGES;
}

__global__ void fill_eids_kernel(const int* __restrict__ eidx, int* __restrict__ ecur,
                                 int* __restrict__ eids){
  const int e = blockIdx.x * 256 + threadIdx.x;
  if (e < EDGES){
    const int p = atomicAdd(&ecur[eidx[e]], 1);
    eids[p] = e;
  }
}

// ======================= gather (segment mean, no atomics) =================

template<int NOUT, bool RES>
__global__ void gather_kernel(const float* __restrict__ tp_out,
    const int* __restrict__ eoff, const int* __restrict__ eids,
    const float* __restrict__ h0, float* __restrict__ out)
{
  const int node = blockIdx.x * 4 + (threadIdx.x >> 6);
  const int lane = threadIdx.x & 63;
  if (node >= NODES) return;
  const int s = eoff[node], e_end = eoff[node+1];
  if (lane < NOUT) {
    float v = 0.f;
    for (int k = s; k < e_end; ++k) {
      const int e = eids[k];
      v += tp_out[(size_t)e*NOUT + lane];
    }
    v /= fmaxf((float)(e_end - s), 1.0f);
    if (RES && lane < 16) v += h0[node*16 + lane];
    out[(size_t)node*NOUT + lane] = v;
  }
}

// ======================= small kernels =====================================

__global__ void lin_kernel(const float* __restrict__ nf, const float* __restrict__ w,
                           const float* __restrict__ b, float* __restrict__ h0){
  const int idx = blockIdx.x * 256 + threadIdx.x;
  if (idx >= NODES * 16) return;
  const int n = idx >> 4, o = idx & 15;
  const float* __restrict__ row = nf + (size_t)n * 256;
  float acc = b[o];
  for (int c = 0; c < 256; ++c) acc = fmaf(row[c], w[c*16 + o], acc);
  h0[idx] = acc;
}

// ======================= launch ============================================

extern "C" void kernel_launch(void* const* d_in, const int* in_sizes, int n_in,
                              void* d_out, int out_size, void* d_ws, size_t ws_size,
                              hipStream_t stream) {
  (void)in_sizes; (void)n_in; (void)out_size; (void)ws_size;
  const float* node_feature = (const float*)d_in[0];
  const float* edge_vec     = (const float*)d_in[1];
  const float* edge_feature = (const float*)d_in[2];
  const int*   edge_index   = (const int*)d_in[3];
  const float* lin_w = (const float*)d_in[4];
  const float* lin_b = (const float*)d_in[5];
  const float* f1w1 = (const float*)d_in[6];
  const float* f1b1 = (const float*)d_in[7];
  const float* f1w2 = (const float*)d_in[8];
  const float* f1b2 = (const float*)d_in[9];
  const float* f2w1 = (const float*)d_in[10];
  const float* f2b1 = (const float*)d_in[11];
  const float* f2w2 = (const float*)d_in[12];
  const float* f2b2 = (const float*)d_in[13];
  const float* f3w1 = (const float*)d_in[14];
  const float* f3b1 = (const float*)d_in[15];
  const float* f3w2 = (const float*)d_in[16];
  const float* f3b2 = (const float*)d_in[17];

  float* ws   = (float*)d_ws;
  float* cg   = ws;                          // 1024
  int*   cnti = (int*)(ws + 1024);           // 30000
  int*   escan= (int*)(ws + 32768);          // 30000
  int*   bsum = (int*)(ws + 65536);          // 128
  int*   boff = (int*)(ws + 65792);          // 128
  int*   eoff = (int*)(ws + 66048);          // 30001
  int*   ecur = (int*)(ws + 98304);          // 30000
  int*   eids = (int*)(ws + 131072);         // 360000
  float* w2h1 = ws + 491072;                 // 32*320 = 10240
  float* w2h2 = ws + 501312;                 // 32*424 = 13568
  float* w2h3 = ws + 514880;                 // 32*216 = 6912
  float* h0   = ws + 524288;                 // 480000
  float* h1   = ws + 1048576;                // 960000
  float* h2p  = ws + 2097152;                // 1440000
  float* tpo  = ws + 3538944;                // 360000*64 max
  float* outp = (float*)d_out;               // 30000*64

  (void)hipMemsetAsync(cnti, 0, NODES * sizeof(int), stream);

  init_cg_kernel<<<18, 256, 0, stream>>>(cg);
  cnt_kernel<<<(EDGES + 255)/256, 256, 0, stream>>>(edge_index, cnti);
  scanA_kernel<<<NB_SCAN, 256, 0, stream>>>(cnti, escan, bsum);
  scanB_kernel<<<1, 128, 0, stream>>>(bsum, boff);
  scanC_kernel<<<NB_SCAN, 256, 0, stream>>>(escan, cnti, boff, eoff, ecur);
  fill_eids_kernel<<<(EDGES + 255)/256, 256, 0, stream>>>(edge_index, ecur, eids);
  lin_kernel<<<(NODES*16 + 255)/256, 256, 0, stream>>>(node_feature, lin_w, lin_b, h0);
  pack_w2_kernel<<<32, 256, 0, stream>>>(f1w2, w2h1, L1::WN);
  pack_w2_kernel<<<32, 256, 0, stream>>>(f2w2, w2h2, L2::WN);
  pack_w2_kernel<<<32, 256, 0, stream>>>(f3w2, w2h3, L3::WN);

  const int egrid = EDGES / EPB;     // 7500, exact
  const int ggrid = (NODES + 3) / 4;

  conv_kernel<L1><<<egrid, 256, 0, stream>>>(h0, edge_vec, edge_feature, edge_index,
                                             f1w1, f1b1, w2h1, f1b2, cg, tpo);
  gather_kernel<32, true><<<ggrid, 256, 0, stream>>>(tpo, eoff, eids, h0, h1);

  conv_kernel<L2><<<egrid, 256, 0, stream>>>(h1, edge_vec, edge_feature, edge_index,
                                             f2w1, f2b1, w2h2, f2b2, cg, tpo);
  gather_kernel<48, false><<<ggrid, 256, 0, stream>>>(tpo, eoff, eids, h0, h2p);

  conv_kernel<L3><<<egrid, 256, 0, stream>>>(h2p, edge_vec, edge_feature, edge_index,
                                             f3w1, f3b1, w2h3, f3b2, cg, tpo);
  gather_kernel<64, false><<<ggrid, 256, 0, stream>>>(tpo, eoff, eids, h0, outp);
}

// Round 14
// 1511.234 us; speedup vs baseline: 1.4716x; 1.4716x over previous
//
#include <hip/hip_runtime.h>
#include <math.h>

#define EDGES 360000
#define NODES 30000
#define NB_SCAN 118   // ceil(30000/256)
#define EPB 48        // edges per block (360000 = 48*7500 exact)

typedef _Float16 h2 __attribute__((ext_vector_type(2)));
typedef _Float16 h8 __attribute__((ext_vector_type(8)));

__device__ inline int imin(int a, int b){ return a < b ? a : b; }
__device__ inline int imax(int a, int b){ return a > b ? a : b; }

__device__ __forceinline__ float fdot2h(h2 a, h2 b, float c){
#if __has_builtin(__builtin_amdgcn_fdot2)
  return __builtin_amdgcn_fdot2(a, b, c, false);
#else
  return c + (float)a[0]*(float)b[0] + (float)a[1]*(float)b[1];
#endif
}

__device__ __forceinline__ float softplusf(float v){
  return fmaxf(v, 0.f) + log1pf(expf(-fabsf(v)));
}

// ======================= Wigner-3j (CG) on-device init ======================

struct cplx { double re, im; };
__device__ inline cplx cmul(cplx a, cplx b){ return { a.re*b.re - a.im*b.im, a.re*b.im + a.im*b.re }; }

__device__ __constant__ double FACT[9] = {1.0,1.0,2.0,6.0,24.0,120.0,720.0,5040.0,40320.0};

__device__ double su2_cg(int j1,int m1,int j2,int m2,int j3,int m3){
  if (m3 != m1 + m2) return 0.0;
  int vmin = imax(imax(-j1 + j2 + m3, -j1 + m1), 0);
  int vmax = imin(imin(j2 + j3 + m1, j3 - j1 + j2), j3 + m3);
  if (vmax < vmin) return 0.0;
  double c = sqrt((2.0*j3 + 1.0) * FACT[j3+j1-j2] * FACT[j3-j1+j2] * FACT[j1+j2-j3]
                  * FACT[j3+m3] * FACT[j3-m3]
                  / (FACT[j1+j2+j3+1] * FACT[j1-m1] * FACT[j1+m1] * FACT[j2-m2] * FACT[j2+m2]));
  double s = 0.0;
  for (int v = vmin; v <= vmax; ++v){
    double t = FACT[j2+j3+m1-v] * FACT[j1-m1+v]
             / (FACT[v] * FACT[j3-j1+j2-v] * FACT[j3+m3-v] * FACT[v+j1-j2-m3]);
    s += (((v + j2 + m2) & 1) ? -t : t);
  }
  return c * s;
}

__device__ cplx qval(int l, int r, int c){
  const double s = 0.7071067811865476;
  int m = r - l;
  cplx v = {0.0, 0.0};
  if (m < 0){
    if      (c == l - m) v = { s, 0.0 };
    else if (c == l + m) v = { 0.0, -s };
  } else if (m == 0){
    if (c == l) v = { 1.0, 0.0 };
  } else {
    double sg = (m & 1) ? -1.0 : 1.0;
    if      (c == l + m) v = { sg*s, 0.0 };
    else if (c == l - m) v = { 0.0, sg*s };
  }
  switch (l & 3){
    case 0: return v;
    case 1: return {  v.im, -v.re };
    case 2: return { -v.re, -v.im };
    default:return { -v.im,  v.re };
  }
}

struct Combo { int l1, l2, l3, off; };
__device__ __constant__ Combo COMBOS[18] = {
  {0,0,0,0},{0,1,1,1},{0,2,2,10},{1,0,1,35},{1,1,0,44},{1,1,1,53},{1,1,2,80},
  {1,2,1,125},{1,2,2,170},{1,2,3,245},{2,0,2,350},{2,1,1,375},{2,1,2,420},
  {2,1,3,495},{2,2,0,600},{2,2,1,625},{2,2,2,700},{2,2,3,825}
};

__global__ void init_cg_kernel(float* __restrict__ cg){
  __shared__ double sr[175], si[175];
  __shared__ double snorm[2];
  const Combo cb = COMBOS[blockIdx.x];
  const int d1 = 2*cb.l1+1, d2 = 2*cb.l2+1, d3 = 2*cb.l3+1;
  const int tot = d1*d2*d3;
  for (int idx = threadIdx.x; idx < tot; idx += blockDim.x){
    int j = idx/(d2*d3), rem = idx - j*(d2*d3);
    int l = rem/d3, m = rem - l*d3;
    double ar = 0.0, ai = 0.0;
    for (int i = 0; i < d1; ++i){
      cplx q1 = qval(cb.l1, i, j);
      if (q1.re == 0.0 && q1.im == 0.0) continue;
      for (int k = 0; k < d2; ++k){
        cplx q2 = qval(cb.l2, k, l);
        if (q2.re == 0.0 && q2.im == 0.0) continue;
        cplx q12 = cmul(q1, q2);
        for (int n = 0; n < d3; ++n){
          double g = su2_cg(cb.l1, i-cb.l1, cb.l2, k-cb.l2, cb.l3, n-cb.l3);
          if (g == 0.0) continue;
          cplx q3 = qval(cb.l3, n, m); q3.im = -q3.im;
          cplx t = cmul(q12, q3);
          ar += t.re * g; ai += t.im * g;
        }
      }
    }
    sr[idx] = ar; si[idx] = ai;
  }
  __syncthreads();
  if (threadIdx.x == 0){
    double nr = 0.0, ni = 0.0;
    for (int t = 0; t < tot; ++t){ nr += sr[t]*sr[t]; ni += si[t]*si[t]; }
    snorm[0] = nr; snorm[1] = ni;
  }
  __syncthreads();
  const bool useR = snorm[0] >= snorm[1];
  const double inv = 1.0 / sqrt(useR ? snorm[0] : snorm[1]);
  for (int idx = threadIdx.x; idx < tot; idx += blockDim.x)
    cg[cb.off + idx] = (float)((useR ? sr[idx] : si[idx]) * inv);
}

// ======================= layer definitions =================================

struct InsT { int l1,l2,l3,m1,m3,s1,s2,so,woff,cg; float alpha; };

struct L1 {
  static constexpr int NIN = 16, NOUT = 32, WN = 320, NI = 3, NWIN = 5, NU = 16, SW = 322;
  static constexpr InsT ins[NI] = {
    {0,0,0,16,16, 0,0, 0,   0,  0, 0.25f},
    {0,1,1,16, 2, 0,1,16, 256,  1, 0.4330127019f},
    {0,2,2,16, 2, 0,4,22, 288, 10, 0.5590169944f},
  };
  static constexpr int uT [NU] = {0,0,0,0,0,0,0,0, 1,1,1,1, 2,2,2,2};
  static constexpr int uCh[NU] = {0,1,2,3,4,5,6,7, 0,1,2,3, 0,1,2,3};
  static constexpr int uD0[NU] = {0,0,0,0,0,0,0,0, 0,0,0,0, 0,0,0,0};
  static constexpr int uND[NU] = {2,2,2,2,2,2,2,2, 4,4,4,4, 4,4,4,4};
  static constexpr int uPt[NU] = {0,0,0,0,0,0,0,0, 1,1,1,1, 2,2,2,2};
};
struct L2 {
  static constexpr int NIN = 32, NOUT = 48, WN = 424, NI = 15, NWIN = 7, NU = 30, SW = 426;
  static constexpr InsT ins[NI] = {
    {0,0,0,16,16, 0,0, 0,   0,  0, 0.2236067977f},
    {0,1,1,16, 2, 0,1,16, 256,  1, 0.3692744729f},
    {0,2,2,16, 2, 0,4,28, 288, 10, 0.4767312946f},
    {1,0,1, 2, 2,16,0,16, 320, 35, 0.3692744729f},
    {1,1,0, 2,16,16,1, 0, 324, 44, 0.2236067977f},
    {1,1,1, 2, 2,16,1,22, 356, 53, 0.8660254038f},
    {1,1,2, 2, 2,16,1,28, 360, 80, 0.4767312946f},
    {1,2,1, 2, 2,16,4,16, 364,125, 0.3692744729f},
    {1,2,2, 2, 2,16,4,38, 368,170, 1.1180339887f},
    {2,0,2, 2, 2,22,0,28, 372,350, 0.4767312946f},
    {2,1,1, 2, 2,22,1,16, 376,375, 0.3692744729f},
    {2,1,2, 2, 2,22,1,38, 380,420, 1.1180339887f},
    {2,2,0, 2,16,22,4, 0, 384,600, 0.2236067977f},
    {2,2,1, 2, 2,22,4,22, 416,625, 0.8660254038f},
    {2,2,2, 2, 2,22,4,28, 420,700, 0.4767312946f},
  };
  static constexpr int uT [NU] = {0,0,0,0,0,0,0,0, 1,1,1,1, 2,2,2,2, 3, 4,4, 5, 6,7,8, 9,10,11, 12,12, 13,14};
  static constexpr int uCh[NU] = {0,1,2,3,4,5,6,7, 0,1,2,3, 0,1,2,3, 0, 0,0, 0, 0,0,0, 0,0,0, 0,0, 0,0};
  static constexpr int uD0[NU] = {0,0,0,0,0,0,0,0, 0,0,0,0, 0,0,0,0, 0, 0,1, 0, 0,0,0, 0,0,0, 0,1, 0,0};
  static constexpr int uND[NU] = {2,2,2,2,2,2,2,2, 4,4,4,4, 4,4,4,4, 2, 1,1, 2, 2,2,2, 2,2,2, 1,1, 2,2};
  static constexpr int uPt[NU] = {0,0,0,0,0,0,0,0, 1,1,1,1, 2,2,2,2, 1, 0,0, 1, 2,1,3, 2,1,3, 0,0, 1,2};
};
struct L3 {
  static constexpr int NIN = 48, NOUT = 64, WN = 216, NI = 33, NWIN = 4, NU = 42, SW = 218;
  static constexpr InsT ins[NI] = {
    {0,0,0,16,2, 0,0, 0,   0,  0, 0.2236067977f},
    {0,1,1,16,2, 0,1,10,  32,  1, 0.3396831102f},
    {0,2,2,16,2, 0,4,16,  64, 10, 0.4385290097f},
    {1,0,1, 2,2,16,0,10,  96, 35, 0.3396831102f},
    {1,1,0, 2,2,16,1, 0, 100, 44, 0.2236067977f},
    {1,1,1, 2,2,16,1, 4, 104, 53, 0.5477225575f},
    {1,1,2, 2,2,16,1,16, 108, 80, 0.4385290097f},
    {1,2,1, 2,2,16,4,10, 112,125, 0.3396831102f},
    {1,2,2, 2,2,16,4,26, 116,170, 0.7071067812f},
    {1,2,3, 2,2,16,4,50, 120,245, 1.0801234497f},
    {1,0,1, 2,2,22,0, 4, 124, 35, 0.5477225575f},
    {1,1,0, 2,2,22,1, 2, 128, 44, 0.5f},
    {1,1,1, 2,2,22,1,10, 132, 53, 0.3396831102f},
    {1,1,2, 2,2,22,1,26, 136, 80, 0.7071067812f},
    {1,2,1, 2,2,22,4, 4, 140,125, 0.5477225575f},
    {1,2,2, 2,2,22,4,16, 144,170, 0.4385290097f},
    {1,2,3, 2,2,22,4,36, 148,245, 1.0801234497f},
    {2,0,2, 2,2,28,0,16, 152,350, 0.4385290097f},
    {2,1,1, 2,2,28,1,10, 156,375, 0.3396831102f},
    {2,1,2, 2,2,28,1,26, 160,420, 0.7071067812f},
    {2,1,3, 2,2,28,1,50, 164,495, 1.0801234497f},
    {2,2,0, 2,2,28,4, 0, 168,600, 0.2236067977f},
    {2,2,1, 2,2,28,4, 4, 172,625, 0.5477225575f},
    {2,2,2, 2,2,28,4,16, 176,700, 0.4385290097f},
    {2,2,3, 2,2,28,4,36, 180,825, 1.0801234497f},
    {2,0,2, 2,2,38,0,26, 184,350, 0.7071067812f},
    {2,1,1, 2,2,38,1, 4, 188,375, 0.5477225575f},
    {2,1,2, 2,2,38,1,16, 192,420, 0.4385290097f},
    {2,1,3, 2,2,38,1,36, 196,495, 1.0801234497f},
    {2,2,0, 2,2,38,4, 2, 200,600, 0.5f},
    {2,2,1, 2,2,38,4,10, 204,625, 0.3396831102f},
    {2,2,2, 2,2,38,4,26, 208,700, 0.7071067812f},
    {2,2,3, 2,2,38,4,50, 212,825, 1.0801234497f},
  };
  static constexpr int uT [NU] = {0,0,0,0, 1,1,1,1, 2,2,2,2,
    3,4,5,6,7,8,9,10,11,12,13,14,15,16,17,18,19,20,21,22,23,24,25,26,27,28,29,30,31,32};
  static constexpr int uCh[NU] = {0,1,2,3, 0,1,2,3, 0,1,2,3,
    0,0,0,0,0,0,0,0,0,0,0,0,0,0,0,0,0,0,0,0,0,0,0,0,0,0,0,0,0,0};
  static constexpr int uD0[NU] = {0,0,0,0, 0,0,0,0, 0,0,0,0,
    0,0,0,0,0,0,0,0,0,0,0,0,0,0,0,0,0,0,0,0,0,0,0,0,0,0,0,0,0,0};
  static constexpr int uND[NU] = {4,4,4,4, 4,4,4,4, 4,4,4,4,
    2,2,2,2,2,2,2,2,2,2,2,2,2,2,2,2,2,2,2,2,2,2,2,2,2,2,2,2,2,2};
  static constexpr int uPt[NU] = {0,0,0,0, 0,0,0,0, 1,1,1,1,
    0,0,0,1,0,1,3,0,0,0,1,0,1,2,1,0,1,3,0,0,1,2,1,0,1,2,0,0,1,3};
};

// ======================= constexpr helpers =================================

template<class LD>
constexpr int colsum(){
  int s = 0;
  for (int u = 0; u < LD::NU; ++u) s += LD::uND[u] * LD::ins[LD::uT[u]].m3;
  return s;
}
static_assert(colsum<L1>() == L1::WN, "L1 col coverage");
static_assert(colsum<L2>() == L2::WN, "L2 col coverage");
static_assert(colsum<L3>() == L3::WN, "L3 col coverage");

template<class LD, int PART>
constexpr int soLo(){
  int lo = 1 << 20;
  for (int u = 0; u < LD::NU; ++u){
    if (LD::uPt[u] != PART) continue;
    const InsT I = LD::ins[LD::uT[u]];
    if (I.so < lo) lo = I.so;
  }
  return lo;
}
template<class LD, int PART>
constexpr int soHi(){
  int hi = 0;
  for (int u = 0; u < LD::NU; ++u){
    if (LD::uPt[u] != PART) continue;
    const InsT I = LD::ins[LD::uT[u]];
    const int e = I.so + I.m3 * (2*I.l3 + 1);
    if (e > hi) hi = e;
  }
  return hi;
}
// contiguous disjoint coverage of [0,NOUT)
static_assert(soLo<L1,0>()==0 && soHi<L1,0>()==soLo<L1,1>() && soHi<L1,1>()==soLo<L1,2>()
           && soHi<L1,2>()==L1::NOUT && soHi<L1,3>()==0, "L1 parts");
static_assert(soLo<L2,0>()==0 && soHi<L2,0>()==soLo<L2,1>() && soHi<L2,1>()==soLo<L2,2>()
           && soHi<L2,2>()==soLo<L2,3>() && soHi<L2,3>()==L2::NOUT, "L2 parts");
static_assert(soLo<L3,0>()==0 && soHi<L3,0>()==soLo<L3,1>() && soHi<L3,1>()==soLo<L3,2>()
           && soHi<L3,2>()==soLo<L3,3>() && soHi<L3,3>()==L3::NOUT, "L3 parts");

// ======================= TP units (register outv, barrier-free) ============

template<class LD, int PART, int U, int NV>
__device__ __forceinline__ void tp_units(const char* wrow,
    const float* arow, const float* __restrict__ cgp,
    const float (&sh)[9], float (&outv)[NV])
{
  if constexpr (U < LD::NU) {
    if constexpr (LD::uPt[U] == PART) {
      constexpr InsT I = LD::ins[LD::uT[U]];
      constexpr int d1 = 2*I.l1+1, d2 = 2*I.l2+1, d3 = 2*I.l3+1;
      constexpr int UCH = (I.m3 == 16) ? 2 : (I.m1 == 16 ? 4 : 2);
      constexpr int base = I.woff + LD::uCh[U] * UCH * I.m3;
      constexpr int SOLO = soLo<LD,PART>();
      constexpr int D0 = LD::uD0[U];
      constexpr int ND = LD::uND[U];
      #pragma unroll
      for (int dd = 0; dd < ND; ++dd) {
        const int du = D0 + dd;
        const int u  = LD::uCh[U]*UCH + du;
        float ab[d3];
        #pragma unroll
        for (int k = 0; k < d3; ++k) ab[k] = 0.f;
        #pragma unroll
        for (int i = 0; i < d1; ++i) {
          const float ai = arow[I.s1 + u*d1 + i];
          #pragma unroll
          for (int j = 0; j < d2; ++j) {
            const float s = ai * sh[I.s2 + j];
            #pragma unroll
            for (int k = 0; k < d3; ++k)
              ab[k] = fmaf(cgp[I.cg + (i*d2 + j)*d3 + k], s, ab[k]);
          }
        }
        #pragma unroll
        for (int wo2 = 0; wo2 < I.m3/2; ++wo2) {
          const h2 wp = *(const h2*)(wrow + (base + du*I.m3 + 2*wo2)*2);
          const float wv0 = I.alpha * (float)wp[0];
          const float wv1 = I.alpha * (float)wp[1];
          #pragma unroll
          for (int k = 0; k < d3; ++k) {
            outv[I.so - SOLO + (2*wo2  )*d3 + k] =
              fmaf(wv0, ab[k], outv[I.so - SOLO + (2*wo2  )*d3 + k]);
            outv[I.so - SOLO + (2*wo2+1)*d3 + k] =
              fmaf(wv1, ab[k], outv[I.so - SOLO + (2*wo2+1)*d3 + k]);
          }
        }
      }
    }
    tp_units<LD, PART, U+1, NV>(wrow, arow, cgp, sh, outv);
  }
}

template<class LD, int PART>
__device__ __forceinline__ void run_part(const char* wrow, const float* arow,
    const float* __restrict__ cgp, const float (&sh)[9], float* dstp)
{
  constexpr int LO = soLo<LD,PART>();
  constexpr int HI = soHi<LD,PART>();
  if constexpr (HI > LO) {
    constexpr int NV = HI - LO;
    float outv[NV] = {};
    tp_units<LD, PART, 0, NV>(wrow, arow, cgp, sh, outv);
    #pragma unroll
    for (int o = 0; o < NV; ++o) dstp[LO + o] = outv[o];
  }
}

// ======================= pack w2 to fp16 pair rows =========================
__global__ void pack_w2_kernel(const float* __restrict__ w2, float* __restrict__ dst,
                               int WN){
  const int hp = blockIdx.x;
  for (int c = threadIdx.x; c < WN; c += 256){
    h2 p;
    p[0] = (_Float16)w2[(size_t)(2*hp  )*WN + c];
    p[1] = (_Float16)w2[(size_t)(2*hp+1)*WN + c];
    *(h2*)((char*)dst + ((size_t)hp*WN + c)*4) = p;
  }
}

// ======================= fused conv kernel =================================
// LDS: Wls [48 e][SW fp16] (∪ efsB) | hidB [32 hp][192B] | asB [48][NIN+1 f]

template<class LD>
__launch_bounds__(256, 3)
__global__ void conv_kernel(const float* __restrict__ node_h,
    const float* __restrict__ edge_vec, const float* __restrict__ edge_feat,
    const int* __restrict__ eidx,
    const float* __restrict__ w1, const float* __restrict__ b1,
    const float* __restrict__ w2h, const float* __restrict__ b2,
    const float* __restrict__ cgp, float* __restrict__ tp_out)
{
  constexpr int NIN = LD::NIN, NOUT = LD::NOUT, WN = LD::WN;
  constexpr int SB = LD::SW * 2;
  constexpr int WBYTES = EPB * SB;
  constexpr int OFF_HID = WBYTES;
  constexpr int OFF_AS  = WBYTES + 32*192;
  constexpr int SM_BYTES = OFF_AS + EPB*(NIN+1)*4;
  static_assert(SM_BYTES <= 65536, "static LDS limit");
  static_assert(32*192 <= WBYTES, "efsB must fit in W region");
  __shared__ __align__(16) char sm[SM_BYTES];
  char* Wls  = sm;
  char* efsB = sm;                  // alias: dead after FC1
  char* hidB = sm + OFF_HID;        // [32 hp][192B]
  float* asB = (float*)(sm + OFF_AS);

  const int t = threadIdx.x;
  const int e0g = blockIdx.x * EPB;

  // ---------- phase 0: stage ef (transposed fp16 pairs) + a (padded) ------
  {
    const float4* efg = (const float4*)edge_feat + (size_t)e0g * 16;
    #pragma unroll
    for (int r = 0; r < 3; ++r) {
      const int f = r*256 + t;                 // f < 768 = 48e*16
      const int e = f >> 4, c0 = (f & 15) * 4;
      const float4 v = efg[f];
      h2 pa; pa[0] = (_Float16)v.x; pa[1] = (_Float16)v.y;
      h2 pb; pb[0] = (_Float16)v.z; pb[1] = (_Float16)v.w;
      *(h2*)(efsB + (c0>>1)*192 + e*4)     = pa;
      *(h2*)(efsB + ((c0>>1)+1)*192 + e*4) = pb;
    }
    for (int i = t; i < EPB*NIN; i += 256) {
      const int e = i / NIN, c = i - e*NIN;
      const int dst = eidx[EDGES + e0g + e];
      asB[e*(NIN+1) + c] = node_h[(size_t)dst*NIN + c];
    }
  }
  __syncthreads();

  // ---------- phase 1: FC1 (hidden = softplus(ef@w1+b1)) -> hidB ----------
  {
    const int hg = t >> 3, eg2 = t & 7;       // hp 0..31, 6 edges each
    const int h0 = hg*2, e0 = eg2*6;
    float acc[2][6];
    const float b10 = b1[h0], b11 = b1[h0+1];
    #pragma unroll
    for (int i = 0; i < 6; ++i) { acc[0][i] = b10; acc[1][i] = b11; }
    for (int cp = 0; cp < 32; ++cp) {
      h2 wp0, wp1;
      wp0[0] = (_Float16)w1[(size_t)(2*cp)*64 + h0];
      wp0[1] = (_Float16)w1[(size_t)(2*cp+1)*64 + h0];
      wp1[0] = (_Float16)w1[(size_t)(2*cp)*64 + h0+1];
      wp1[1] = (_Float16)w1[(size_t)(2*cp+1)*64 + h0+1];
      #pragma unroll
      for (int i = 0; i < 6; ++i) {
        const h2 e2 = *(const h2*)(efsB + cp*192 + (e0+i)*4);
        acc[0][i] = fdot2h(wp0, e2, acc[0][i]);
        acc[1][i] = fdot2h(wp1, e2, acc[1][i]);
      }
    }
    __syncthreads();   // all efsB reads done -> W region writable
    #pragma unroll
    for (int i = 0; i < 6; ++i) {
      h2 p;
      p[0] = (_Float16)softplusf(acc[0][i]);
      p[1] = (_Float16)softplusf(acc[1][i]);
      *(h2*)(hidB + hg*192 + (e0+i)*4) = p;
    }
  }
  __syncthreads();     // hidB complete

  // ---------- phase 2: FC2 over ALL columns -> W LDS (no barriers) --------
  {
    const int eg = t >> 4, cg = t & 15;       // 16 edge-groups x 3e, 16 col-groups x 4c
    const int e0 = eg*3;
    #pragma unroll
    for (int k = 0; k < LD::NWIN; ++k) {
      const int cb = k*64 + cg*4;
      if (cb < WN) {
        float acc[3][4];
        const float4 bv = *(const float4*)&b2[cb];
        const float bb[4] = {bv.x, bv.y, bv.z, bv.w};
        #pragma unroll
        for (int ei = 0; ei < 3; ++ei)
          #pragma unroll
          for (int ci = 0; ci < 4; ++ci) acc[ei][ci] = bb[ci];
        for (int hp = 0; hp < 32; ++hp) {
          const h8 wv = *(const h8*)((const char*)w2h + ((size_t)hp*WN + cb)*4);
          const h2 h0v = *(const h2*)(hidB + hp*192 + (e0+0)*4);
          const h2 h1v = *(const h2*)(hidB + hp*192 + (e0+1)*4);
          const h2 h2v = *(const h2*)(hidB + hp*192 + (e0+2)*4);
          #pragma unroll
          for (int ci = 0; ci < 4; ++ci) {
            const h2 wp = ((const h2*)&wv)[ci];
            acc[0][ci] = fdot2h(h0v, wp, acc[0][ci]);
            acc[1][ci] = fdot2h(h1v, wp, acc[1][ci]);
            acc[2][ci] = fdot2h(h2v, wp, acc[2][ci]);
          }
        }
        #pragma unroll
        for (int ei = 0; ei < 3; ++ei) {
          char* wp = Wls + (e0+ei)*SB + cb*2;
          h2 p0; p0[0] = (_Float16)acc[ei][0]; p0[1] = (_Float16)acc[ei][1];
          h2 p1; p1[0] = (_Float16)acc[ei][2]; p1[1] = (_Float16)acc[ei][3];
          *(h2*)(wp)     = p0;
          *(h2*)(wp + 4) = p1;
        }
      }
    }
  }
  __syncthreads();     // W complete — LAST barrier

  // ---------- phase 3: TP, 4 channel-parts (one wave each), barrier-free --
  const int wave = t >> 6;
  const int lane = t & 63;
  if (lane < EPB) {
    const int le = lane;
    const int eme = e0g + le;
    float sh[9];
    {
      const float vx = edge_vec[(size_t)eme*3 + 0];
      const float vy = edge_vec[(size_t)eme*3 + 1];
      const float vz = edge_vec[(size_t)eme*3 + 2];
      const float nrm = sqrtf(vx*vx + vy*vy + vz*vz);
      const float invn = 1.0f / fmaxf(nrm, 1e-12f);
      const float x = vx*invn, y = vy*invn, z = vz*invn;
      sh[0] = 1.0f;
      sh[1] = 1.7320508076f * y;
      sh[2] = 1.7320508076f * z;
      sh[3] = 1.7320508076f * x;
      sh[4] = 3.8729833462f * x * y;
      sh[5] = 3.8729833462f * y * z;
      sh[6] = 1.1180339887f * (3.0f*z*z - 1.0f);
      sh[7] = 3.8729833462f * x * z;
      sh[8] = 1.9364916731f * (x*x - y*y);
    }
    const char* wrow  = Wls + le * SB;
    const float* arow = asB + le * (NIN + 1);
    float* dstp = tp_out + (size_t)eme * NOUT;
    switch (wave) {
      case 0:  run_part<LD,0>(wrow, arow, cgp, sh, dstp); break;
      case 1:  run_part<LD,1>(wrow, arow, cgp, sh, dstp); break;
      case 2:  run_part<LD,2>(wrow, arow, cgp, sh, dstp); break;
      default: run_part<LD,3>(wrow, arow, cgp, sh, dstp); break;
    }
  }
}

// ======================= CSR build kernels =================================

__global__ void cnt_kernel(const int* __restrict__ eidx, int* __restrict__ cnti){
  const int e = blockIdx.x * 256 + threadIdx.x;
  if (e < EDGES) atomicAdd(&cnti[eidx[e]], 1);
}

__global__ void scanA_kernel(const int* __restrict__ cnti, int* __restrict__ escan,
                             int* __restrict__ bsum){
  __shared__ int s[256];
  const int t = threadIdx.x, idx = blockIdx.x*256 + t;
  int v = (idx < NODES) ? cnti[idx] : 0;
  s[t] = v; __syncthreads();
  for (int off = 1; off < 256; off <<= 1){
    int x = (t >= off) ? s[t-off] : 0;
    __syncthreads();
    s[t] += x;
    __syncthreads();
  }
  if (idx < NODES) escan[idx] = s[t];
  if (t == 255) bsum[blockIdx.x] = s[255];
}

__global__ void scanB_kernel(const int* __restrict__ bsum, int* __restrict__ boff){
  __shared__ int s[128];
  const int t = threadIdx.x;
  int v = (t < NB_SCAN) ? bsum[t] : 0;
  s[t] = v; __syncthreads();
  for (int off = 1; off < 128; off <<= 1){
    int x = (t >= off) ? s[t-off] : 0;
    __syncthreads();
    s[t] += x;
    __syncthreads();
  }
  if (t < NB_SCAN) boff[t] = s[t] - v;   // exclusive
}

__global__ void scanC_kernel(const int* __restrict__ escan, const int* __restrict__ cnti,
                             const int* __restrict__ boff, int* __restrict__ eoff,
                             int* __restrict__ ecur){
  const int idx = blockIdx.x*256 + threadIdx.x;
  if (idx < NODES){
    const int v = escan[idx] - cnti[idx] + boff[blockIdx.x];
    eoff[idx] = v; ecur[idx] = v;
  }
  if (idx == 0) eoff[NODES] = EDGES;
}

__global__ void fill_eids_kernel(const int* __restrict__ eidx, int* __restrict__ ecur,
                                 int* __restrict__ eids){
  const int e = blockIdx.x * 256 + threadIdx.x;
  if (e < EDGES){
    const int p = atomicAdd(&ecur[eidx[e]], 1);
    eids[p] = e;
  }
}

// ======================= gather (segment mean, no atomics) =================

template<int NOUT, bool RES>
__global__ void gather_kernel(const float* __restrict__ tp_out,
    const int* __restrict__ eoff, const int* __restrict__ eids,
    const float* __restrict__ h0, float* __restrict__ out)
{
  const int node = blockIdx.x * 4 + (threadIdx.x >> 6);
  const int lane = threadIdx.x & 63;
  if (node >= NODES) return;
  const int s = eoff[node], e_end = eoff[node+1];
  if (lane < NOUT) {
    float v = 0.f;
    for (int k = s; k < e_end; ++k) {
      const int e = eids[k];
      v += tp_out[(size_t)e*NOUT + lane];
    }
    v /= fmaxf((float)(e_end - s), 1.0f);
    if (RES && lane < 16) v += h0[node*16 + lane];
    out[(size_t)node*NOUT + lane] = v;
  }
}

// ======================= small kernels =====================================

__global__ void lin_kernel(const float* __restrict__ nf, const float* __restrict__ w,
                           const float* __restrict__ b, float* __restrict__ h0){
  const int idx = blockIdx.x * 256 + threadIdx.x;
  if (idx >= NODES * 16) return;
  const int n = idx >> 4, o = idx & 15;
  const float* __restrict__ row = nf + (size_t)n * 256;
  float acc = b[o];
  for (int c = 0; c < 256; ++c) acc = fmaf(row[c], w[c*16 + o], acc);
  h0[idx] = acc;
}

// ======================= launch ============================================

extern "C" void kernel_launch(void* const* d_in, const int* in_sizes, int n_in,
                              void* d_out, int out_size, void* d_ws, size_t ws_size,
                              hipStream_t stream) {
  (void)in_sizes; (void)n_in; (void)out_size; (void)ws_size;
  const float* node_feature = (const float*)d_in[0];
  const float* edge_vec     = (const float*)d_in[1];
  const float* edge_feature = (const float*)d_in[2];
  const int*   edge_index   = (const int*)d_in[3];
  const float* lin_w = (const float*)d_in[4];
  const float* lin_b = (const float*)d_in[5];
  const float* f1w1 = (const float*)d_in[6];
  const float* f1b1 = (const float*)d_in[7];
  const float* f1w2 = (const float*)d_in[8];
  const float* f1b2 = (const float*)d_in[9];
  const float* f2w1 = (const float*)d_in[10];
  const float* f2b1 = (const float*)d_in[11];
  const float* f2w2 = (const float*)d_in[12];
  const float* f2b2 = (const float*)d_in[13];
  const float* f3w1 = (const float*)d_in[14];
  const float* f3b1 = (const float*)d_in[15];
  const float* f3w2 = (const float*)d_in[16];
  const float* f3b2 = (const float*)d_in[17];

  float* ws   = (float*)d_ws;
  float* cg   = ws;                          // 1024
  int*   cnti = (int*)(ws + 1024);           // 30000
  int*   escan= (int*)(ws + 32768);          // 30000
  int*   bsum = (int*)(ws + 65536);          // 128
  int*   boff = (int*)(ws + 65792);          // 128
  int*   eoff = (int*)(ws + 66048);          // 30001
  int*   ecur = (int*)(ws + 98304);          // 30000
  int*   eids = (int*)(ws + 131072);         // 360000
  float* w2h1 = ws + 491072;                 // 32*320 = 10240
  float* w2h2 = ws + 501312;                 // 32*424 = 13568
  float* w2h3 = ws + 514880;                 // 32*216 = 6912
  float* h0   = ws + 524288;                 // 480000
  float* h1   = ws + 1048576;                // 960000
  float* h2p  = ws + 2097152;                // 1440000
  float* tpo  = ws + 3538944;                // 360000*64 max
  float* outp = (float*)d_out;               // 30000*64

  (void)hipMemsetAsync(cnti, 0, NODES * sizeof(int), stream);

  init_cg_kernel<<<18, 256, 0, stream>>>(cg);
  cnt_kernel<<<(EDGES + 255)/256, 256, 0, stream>>>(edge_index, cnti);
  scanA_kernel<<<NB_SCAN, 256, 0, stream>>>(cnti, escan, bsum);
  scanB_kernel<<<1, 128, 0, stream>>>(bsum, boff);
  scanC_kernel<<<NB_SCAN, 256, 0, stream>>>(escan, cnti, boff, eoff, ecur);
  fill_eids_kernel<<<(EDGES + 255)/256, 256, 0, stream>>>(edge_index, ecur, eids);
  lin_kernel<<<(NODES*16 + 255)/256, 256, 0, stream>>>(node_feature, lin_w, lin_b, h0);
  pack_w2_kernel<<<32, 256, 0, stream>>>(f1w2, w2h1, L1::WN);
  pack_w2_kernel<<<32, 256, 0, stream>>>(f2w2, w2h2, L2::WN);
  pack_w2_kernel<<<32, 256, 0, stream>>>(f3w2, w2h3, L3::WN);

  const int egrid = EDGES / EPB;     // 7500, exact
  const int ggrid = (NODES + 3) / 4;

  conv_kernel<L1><<<egrid, 256, 0, stream>>>(h0, edge_vec, edge_feature, edge_index,
                                             f1w1, f1b1, w2h1, f1b2, cg, tpo);
  gather_kernel<32, true><<<ggrid, 256, 0, stream>>>(tpo, eoff, eids, h0, h1);

  conv_kernel<L2><<<egrid, 256, 0, stream>>>(h1, edge_vec, edge_feature, edge_index,
                                             f2w1, f2b1, w2h2, f2b2, cg, tpo);
  gather_kernel<48, false><<<ggrid, 256, 0, stream>>>(tpo, eoff, eids, h0, h2p);

  conv_kernel<L3><<<egrid, 256, 0, stream>>>(h2p, edge_vec, edge_feature, edge_index,
                                             f3w1, f3b1, w2h3, f3b2, cg, tpo);
  gather_kernel<64, false><<<ggrid, 256, 0, stream>>>(tpo, eoff, eids, h0, outp);
}